// Round 7
// baseline (235.524 us; speedup 1.0000x reference)
//
#include <hip/hip_runtime.h>
#include <hip/hip_fp8.h>
#include <stdint.h>

#define EPS 1e-8f

constexpr int C  = 256;     // channels (K dim)
constexpr int HW = 16384;   // pixels per image (M and N dims)
constexpr int BM = 128, BN = 128;

typedef __attribute__((ext_vector_type(4))) float floatx4;
typedef long long llong2 __attribute__((ext_vector_type(2)));   // 16B = 2 fp8 k-chunks
typedef unsigned char u8;
typedef unsigned int u32;
typedef unsigned long long u64;

__device__ inline u8 f2fp8(float x) {   // OCP e4m3 (gfx950 HW cvt)
    __hip_fp8_e4m3 h(x);
    return h.__x;
}

// ---------------------------------------------------------------------------
// PREP: one pass over a,b. Per block: 32 pixels x full C (8 c-chunks of 32).
//  - b: stash 32 ch/thread in regs -> sumsq_b -> inv_nb -> fp8 fragment store
//  - a: raw (argmax is scale-invariant per p): convert on the fly + sumsq_a
// Fragment layout (matches gemm loads): slab (g = p>>4, cp = cc>>6) is 1KB;
// element (p, cc) at (g*4+cp)*1024 + lane2*16 + half*8 + j,
// lane2 = (p&15) + ((cb&3)<<4), half = (cc>>5)&1, j = cc&7, cb = cc>>3.
__global__ void prep_kernel(const float* __restrict__ a, const float* __restrict__ b,
                            float* __restrict__ sumsq_a, float* __restrict__ sumsq_b,
                            u8* __restrict__ aF, u8* __restrict__ bF) {
    __shared__ float red[8][32];
    const int tid = threadIdx.x;
    const int tc = tid >> 5, px = tid & 31;
    const int p = blockIdx.x * 32 + px;
    const int g = p >> 4;

    // ---- b: read 32 channels into regs, sumsq
    float bv[32]; float sb = 0.f;
    #pragma unroll
    for (int i = 0; i < 32; ++i) {
        float v = b[(size_t)(tc * 32 + i) * HW + p];
        bv[i] = v; sb += v * v;
    }
    red[tc][px] = sb;
    __syncthreads();
    float B = 0.f;
    #pragma unroll
    for (int j = 0; j < 8; ++j) B += red[j][px];
    if (tid < 32) sumsq_b[p] = B;
    float invb = 1.0f / (sqrtf(B + EPS) + EPS);
    __syncthreads();   // red reused below

    #pragma unroll
    for (int k = 0; k < 4; ++k) {
        int cb = tc * 4 + k;                     // 8-channel block, 0..31
        u64 wv = 0;
        #pragma unroll
        for (int j = 0; j < 8; ++j)
            wv |= (u64)f2fp8(bv[k * 8 + j] * invb) << (8 * j);
        int lane2 = (p & 15) + ((cb & 3) << 4);
        *(u64*)(bF + (((size_t)(g * 4 + (cb >> 3))) << 10) + lane2 * 16 + ((cb >> 2) & 1) * 8) = wv;
    }

    // ---- a: read, convert raw, accumulate sumsq
    float sa = 0.f;
    #pragma unroll
    for (int k = 0; k < 4; ++k) {
        int cb = tc * 4 + k;
        u64 wv = 0;
        #pragma unroll
        for (int j = 0; j < 8; ++j) {
            float v = a[(size_t)(cb * 8 + j) * HW + p];
            sa += v * v;
            wv |= (u64)f2fp8(v) << (8 * j);
        }
        int lane2 = (p & 15) + ((cb & 3) << 4);
        *(u64*)(aF + (((size_t)(g * 4 + (cb >> 3))) << 10) + lane2 * 16 + ((cb >> 2) & 1) * 8) = wv;
    }
    red[tc][px] = sa;
    __syncthreads();
    if (tid < 32) {
        float A = 0.f;
        #pragma unroll
        for (int j = 0; j < 8; ++j) A += red[j][px];
        sumsq_a[p] = A;
    }
}

// ---------------------------------------------------------------------------
// G: fused GEMM (S = A . B^T over K=256, fp8 e4m3) + per-row argmax.
// Barrier-free, LDS-free: fragments load directly global->VGPR (verified R5/R6),
// argmax reduced over ni in regs, over r15 via 4 in-wave shfl_xor steps
// (d<16 stays inside the q4 group), then 1 atomicMax per row per wave.
// No LDS => residency is VGPR-limited (~7 blocks/CU) for full VMEM overlap.
__global__ __launch_bounds__(256) void gemm_argmax(const u8* __restrict__ aF,
                                                   const u8* __restrict__ bF,
                                                   u64* __restrict__ packed) {
    const int tid = threadIdx.x;
    const int w = tid >> 6, lane = tid & 63;
    const int q4 = lane >> 4, r15 = lane & 15;
    const int wm = w >> 1, wn = w & 1;

    const u32 bid = blockIdx.x;
    const u32 xcd = bid & 7, local = bid >> 3;
    const int mt = (int)(xcd * 16 + (local & 15));   // M-stripe per XCD (L2 locality)
    const int nt = (int)(local >> 4);                // slow N sweep
    const int p0 = mt * BM, q0 = nt * BN;

    // wave (wm,wn): A groups mt*8 + wm*4 + mi; fragment (x, cp) at +(x*4+cp)*1KB
    const u8* gA = aF + ((size_t)(mt * 8 + wm * 4) * 4) * 1024 + (u32)lane * 16;
    const u8* gB = bF + ((size_t)(nt * 8 + wn * 4) * 4) * 1024 + (u32)lane * 16;

    floatx4 acc[4][4] = {};
    llong2 afr[2][4], bfr[2][4];
    #pragma unroll
    for (int x = 0; x < 4; ++x) {
        afr[0][x] = *(const llong2*)(gA + (u32)(x * 4) * 1024);
        bfr[0][x] = *(const llong2*)(gB + (u32)(x * 4) * 1024);
    }
    #pragma unroll
    for (int cp = 0; cp < 4; ++cp) {
        const int cur = cp & 1, nxt = cur ^ 1;
        if (cp < 3) {
            #pragma unroll
            for (int x = 0; x < 4; ++x) {
                afr[nxt][x] = *(const llong2*)(gA + (u32)(x * 4 + cp + 1) * 1024);
                bfr[nxt][x] = *(const llong2*)(gB + (u32)(x * 4 + cp + 1) * 1024);
            }
        }
        #pragma unroll
        for (int mi = 0; mi < 4; ++mi)
            #pragma unroll
            for (int ni = 0; ni < 4; ++ni)
                acc[mi][ni] = __builtin_amdgcn_mfma_f32_16x16x32_fp8_fp8(
                    afr[cur][mi].x, bfr[cur][ni].x, acc[mi][ni], 0, 0, 0);
        #pragma unroll
        for (int mi = 0; mi < 4; ++mi)
            #pragma unroll
            for (int ni = 0; ni < 4; ++ni)
                acc[mi][ni] = __builtin_amdgcn_mfma_f32_16x16x32_fp8_fp8(
                    afr[cur][mi].y, bfr[cur][ni].y, acc[mi][ni], 0, 0, 0);
    }

    // epilogue: per-lane argmax over ni, shuffle-reduce over r15, atomicMax.
    // D layout: col = lane&15 (n), row = q4*4+reg (m) — dtype-independent.
    #pragma unroll
    for (int mi = 0; mi < 4; ++mi) {
        #pragma unroll
        for (int reg = 0; reg < 4; ++reg) {
            float bv = acc[mi][0][reg];
            u32 bq = (u32)(q0 + wn * 64 + r15);
            #pragma unroll
            for (int ni = 1; ni < 4; ++ni) {
                float v = acc[mi][ni][reg];
                u32 qc = (u32)(q0 + wn * 64 + ni * 16 + r15);
                bool gt = v > bv;              // strict: ties keep smaller q
                bv = gt ? v : bv;
                bq = gt ? qc : bq;
            }
            u32 m = __float_as_uint(bv);
            m = m ^ (u32)(((int)m >> 31) | 0x80000000u);   // monotone map
            u64 pk = ((u64)m << 32) | (u64)(0xFFFFFFFFu - bq);
            #pragma unroll
            for (int d = 1; d < 16; d <<= 1) {
                u64 o = __shfl_xor((unsigned long long)pk, d);
                pk = o > pk ? o : pk;
            }
            if (r15 == 0)
                atomicMax(&packed[p0 + wm * 64 + mi * 16 + q4 * 4 + reg], pk);
        }
    }
}

// ---------------------------------------------------------------------------
// L: loss from the argmax's own similarity value (no gather!).
// s = a_p . b_hat_q  (fp8 GEMM value, recovered exactly from packed);
// dot(a,b_q) = s * (sqrt(B_q+EPS)+EPS);  cossim = dot/((sqrt(A_p)+EPS)(sqrt(B_q)+EPS)).
__global__ void loss_kernel(const u64* __restrict__ packed,
                            const float* __restrict__ sumsq_a, const float* __restrict__ sumsq_b,
                            float* __restrict__ out) {
    int p = blockIdx.x * 256 + threadIdx.x;
    u64 pk = packed[p];
    u32 m = (u32)(pk >> 32);
    u32 u = (m & 0x80000000u) ? (m ^ 0x80000000u) : ~m;   // inverse monotone map
    float s = __uint_as_float(u);
    u32 q = 0xFFFFFFFFu - (u32)(pk & 0xFFFFFFFFull);
    float A = sumsq_a[p], B = sumsq_b[q];
    float dot = s * (sqrtf(B + EPS) + EPS);
    float cossim = dot / ((sqrtf(A) + EPS) * (sqrtf(B) + EPS));
    float v = (1.0f - cossim) * (1.0f / (float)HW);
    #pragma unroll
    for (int d = 1; d < 64; d <<= 1) v += __shfl_xor(v, d);
    if ((threadIdx.x & 63) == 0) atomicAdd(out, v);
}

// ---------------------------------------------------------------------------
extern "C" void kernel_launch(void* const* d_in, const int* in_sizes, int n_in,
                              void* d_out, int out_size, void* d_ws, size_t ws_size,
                              hipStream_t stream) {
    const float* a = (const float*)d_in[0];
    const float* b = (const float*)d_in[1];
    float* out = (float*)d_out;
    char* ws = (char*)d_ws;

    u8*    aF      = (u8*)ws;                                    // 4 MB
    u8*    bF      = (u8*)(ws + (size_t)4 * 1024 * 1024);        // 4 MB
    float* sumsq_a = (float*)(ws + (size_t)8 * 1024 * 1024);     // 64 KB
    float* sumsq_b = sumsq_a + HW;
    u64*   packed  = (u64*)(sumsq_b + HW);                       // 128 KB

    hipMemsetAsync(out, 0, sizeof(float), stream);
    hipMemsetAsync(packed, 0, (size_t)HW * sizeof(u64), stream);

    prep_kernel<<<dim3(HW / 32), 256, 0, stream>>>(a, b, sumsq_a, sumsq_b, aF, bF);
    gemm_argmax<<<dim3((HW / BM) * (HW / BN)), 256, 0, stream>>>(aF, bF, packed);
    loss_kernel<<<dim3(HW / 256), 256, 0, stream>>>(packed, sumsq_a, sumsq_b, out);
}

// Round 8
// 175.785 us; speedup vs baseline: 1.3398x; 1.3398x over previous
//
#include <hip/hip_runtime.h>
#include <hip/hip_fp8.h>
#include <stdint.h>

#define EPS 1e-8f

constexpr int C  = 256;     // channels (K dim)
constexpr int HW = 16384;   // pixels per image (M and N dims)
constexpr int BM = 128;     // block M tile
constexpr int NG = 2048;    // n-group width per block (16 q-subtiles of 128)

typedef __attribute__((ext_vector_type(4))) float floatx4;
typedef long long llong2 __attribute__((ext_vector_type(2)));   // 16B = 2 fp8 k-chunks
typedef unsigned char u8;
typedef unsigned int u32;
typedef unsigned long long u64;

__device__ inline u8 f2fp8(float x) {   // OCP e4m3 (gfx950 HW cvt)
    __hip_fp8_e4m3 h(x);
    return h.__x;
}

// ---------------------------------------------------------------------------
// PREP (verified R7): one pass over a,b -> sumsq_a/b + fp8 fragment arrays.
// Fragment layout: slab (g = p>>4, cp = cc>>6) is 1KB; element (p, cc) at
// (g*4+cp)*1024 + lane2*16 + half*8 + j, lane2 = (p&15)+((cb&3)<<4),
// half = (cc>>5)&1, j = cc&7, cb = cc>>3.  b normalized, a raw.
__global__ void prep_kernel(const float* __restrict__ a, const float* __restrict__ b,
                            float* __restrict__ sumsq_a, float* __restrict__ sumsq_b,
                            u8* __restrict__ aF, u8* __restrict__ bF) {
    __shared__ float red[8][32];
    const int tid = threadIdx.x;
    const int tc = tid >> 5, px = tid & 31;
    const int p = blockIdx.x * 32 + px;
    const int g = p >> 4;

    float bv[32]; float sb = 0.f;
    #pragma unroll
    for (int i = 0; i < 32; ++i) {
        float v = b[(size_t)(tc * 32 + i) * HW + p];
        bv[i] = v; sb += v * v;
    }
    red[tc][px] = sb;
    __syncthreads();
    float B = 0.f;
    #pragma unroll
    for (int j = 0; j < 8; ++j) B += red[j][px];
    if (tid < 32) sumsq_b[p] = B;
    float invb = 1.0f / (sqrtf(B + EPS) + EPS);
    __syncthreads();   // red reused below

    #pragma unroll
    for (int k = 0; k < 4; ++k) {
        int cb = tc * 4 + k;
        u64 wv = 0;
        #pragma unroll
        for (int j = 0; j < 8; ++j)
            wv |= (u64)f2fp8(bv[k * 8 + j] * invb) << (8 * j);
        int lane2 = (p & 15) + ((cb & 3) << 4);
        *(u64*)(bF + (((size_t)(g * 4 + (cb >> 3))) << 10) + lane2 * 16 + ((cb >> 2) & 1) * 8) = wv;
    }

    float sa = 0.f;
    #pragma unroll
    for (int k = 0; k < 4; ++k) {
        int cb = tc * 4 + k;
        u64 wv = 0;
        #pragma unroll
        for (int j = 0; j < 8; ++j) {
            float v = a[(size_t)(cb * 8 + j) * HW + p];
            sa += v * v;
            wv |= (u64)f2fp8(v) << (8 * j);
        }
        int lane2 = (p & 15) + ((cb & 3) << 4);
        *(u64*)(aF + (((size_t)(g * 4 + (cb >> 3))) << 10) + lane2 * 16 + ((cb >> 2) & 1) * 8) = wv;
    }
    red[tc][px] = sa;
    __syncthreads();
    if (tid < 32) {
        float A = 0.f;
        #pragma unroll
        for (int j = 0; j < 8; ++j) A += red[j][px];
        sumsq_a[p] = A;
    }
}

// ---------------------------------------------------------------------------
// G: fused GEMM + argmax, register-resident A with N-loop.
// grid = 128 m-tiles x 8 n-groups. Block = 4 waves (2m x 2n), wave tile
// 64 rows x 64 cols per q-subtile. A fragments (4 mi x 4 cp x 16B) loaded
// ONCE into VGPRs; loop over 16 q-subtiles of 128 cols, double-buffering B
// fragments (4 ni x 16B per chunk-pair). Running per-lane argmax across the
// whole 2048-col sweep; one shuffle-reduce + atomicMax per row at the end
// (262K atomics total vs R7's 4.2M — the WRITE_SIZE regression).
// ng = bid&7 pins each n-group's 512KB of bF to one XCD's L2.
__global__ __launch_bounds__(256, 2) void gemm_argmax(const u8* __restrict__ aF,
                                                      const u8* __restrict__ bF,
                                                      u64* __restrict__ packed) {
    const int tid = threadIdx.x;
    const int w = tid >> 6, lane = tid & 63;
    const int q4 = lane >> 4, r15 = lane & 15;
    const int wm = w >> 1, wn = w & 1;

    const u32 bid = blockIdx.x;
    const u32 ng = bid & 7;          // n-group -> XCD (L2-resident B)
    const u32 mt = bid >> 3;         // 0..127 M tile
    const int p0 = (int)mt * BM;

    // A fragments resident in VGPRs: frag (mi, cp) = 16B covering k-chunks 2cp,2cp+1
    const u8* gA = aF + ((size_t)(mt * 8 + wm * 4) * 4) * 1024 + (u32)lane * 16;
    llong2 Afr[4][4];
    #pragma unroll
    for (int mi = 0; mi < 4; ++mi)
        #pragma unroll
        for (int cp = 0; cp < 4; ++cp)
            Afr[mi][cp] = *(const llong2*)(gA + (u32)(mi * 4 + cp) * 1024);

    // B base: group (ng*128 + qt*8 + wn*4 + ni), frag (.., cp) -> byte offset
    // qt*32768 + (ni*4+cp)*1024 from this base.
    const u8* gB = bF + ((size_t)(ng * 128 + wn * 4)) * 4096 + (u32)lane * 16;

    float bestv[4][4];
    u32   bestq[4][4];
    #pragma unroll
    for (int mi = 0; mi < 4; ++mi)
        #pragma unroll
        for (int reg = 0; reg < 4; ++reg) { bestv[mi][reg] = -3.4e38f; bestq[mi][reg] = 0; }

    const u32 qlane = ng * 2048 + wn * 64 + (u32)r15;   // + qt*128 + ni*16

    llong2 Bfr[2][4];
    #pragma unroll
    for (int ni = 0; ni < 4; ++ni)
        Bfr[0][ni] = *(const llong2*)(gB + (u32)(ni * 4) * 1024);

    for (int qt = 0; qt < 16; ++qt) {
        floatx4 acc[4][4] = {};
        #pragma unroll
        for (int cp = 0; cp < 4; ++cp) {
            const int cur = cp & 1, nxt = cur ^ 1;
            // prefetch next chunk-pair (crossing into next q-subtile at cp==3)
            u32 nqt = (cp == 3) ? (u32)(qt + 1 < 16 ? qt + 1 : 15) : (u32)qt;
            u32 ncp = (cp == 3) ? 0u : (u32)(cp + 1);
            #pragma unroll
            for (int ni = 0; ni < 4; ++ni)
                Bfr[nxt][ni] = *(const llong2*)(gB + nqt * 32768u + (ncp + (u32)ni * 4) * 1024u);
            #pragma unroll
            for (int mi = 0; mi < 4; ++mi)
                #pragma unroll
                for (int ni = 0; ni < 4; ++ni)
                    acc[mi][ni] = __builtin_amdgcn_mfma_f32_16x16x32_fp8_fp8(
                        Afr[mi][cp].x, Bfr[cur][ni].x, acc[mi][ni], 0, 0, 0);
            #pragma unroll
            for (int mi = 0; mi < 4; ++mi)
                #pragma unroll
                for (int ni = 0; ni < 4; ++ni)
                    acc[mi][ni] = __builtin_amdgcn_mfma_f32_16x16x32_fp8_fp8(
                        Afr[mi][cp].y, Bfr[cur][ni].y, acc[mi][ni], 0, 0, 0);
        }
        // running argmax update (ascending q scan => strict > keeps first min)
        #pragma unroll
        for (int mi = 0; mi < 4; ++mi)
            #pragma unroll
            for (int ni = 0; ni < 4; ++ni) {
                u32 qc = qlane + (u32)qt * 128 + (u32)ni * 16;
                #pragma unroll
                for (int reg = 0; reg < 4; ++reg) {
                    float v = acc[mi][ni][reg];
                    bool gt = v > bestv[mi][reg];
                    bestv[mi][reg] = gt ? v : bestv[mi][reg];
                    bestq[mi][reg] = gt ? qc : bestq[mi][reg];
                }
            }
    }

    // final: pack, shuffle-reduce over r15 (stays in q4 group), 1 atomic/row/wave
    #pragma unroll
    for (int mi = 0; mi < 4; ++mi)
        #pragma unroll
        for (int reg = 0; reg < 4; ++reg) {
            u32 m = __float_as_uint(bestv[mi][reg]);
            m = m ^ (u32)(((int)m >> 31) | 0x80000000u);   // monotone map
            u64 pk = ((u64)m << 32) | (u64)(0xFFFFFFFFu - bestq[mi][reg]);
            #pragma unroll
            for (int d = 1; d < 16; d <<= 1) {
                u64 o = __shfl_xor((unsigned long long)pk, d);
                pk = o > pk ? o : pk;
            }
            if (r15 == 0)
                atomicMax(&packed[p0 + wm * 64 + mi * 16 + q4 * 4 + reg], pk);
        }
}

// ---------------------------------------------------------------------------
// L (verified R7): loss from the argmax's own similarity value (no gather).
__global__ void loss_kernel(const u64* __restrict__ packed,
                            const float* __restrict__ sumsq_a, const float* __restrict__ sumsq_b,
                            float* __restrict__ out) {
    int p = blockIdx.x * 256 + threadIdx.x;
    u64 pk = packed[p];
    u32 m = (u32)(pk >> 32);
    u32 u = (m & 0x80000000u) ? (m ^ 0x80000000u) : ~m;   // inverse monotone map
    float s = __uint_as_float(u);
    u32 q = 0xFFFFFFFFu - (u32)(pk & 0xFFFFFFFFull);
    float A = sumsq_a[p], B = sumsq_b[q];
    float dot = s * (sqrtf(B + EPS) + EPS);
    float cossim = dot / ((sqrtf(A) + EPS) * (sqrtf(B) + EPS));
    float v = (1.0f - cossim) * (1.0f / (float)HW);
    #pragma unroll
    for (int d = 1; d < 64; d <<= 1) v += __shfl_xor(v, d);
    if ((threadIdx.x & 63) == 0) atomicAdd(out, v);
}

// ---------------------------------------------------------------------------
extern "C" void kernel_launch(void* const* d_in, const int* in_sizes, int n_in,
                              void* d_out, int out_size, void* d_ws, size_t ws_size,
                              hipStream_t stream) {
    const float* a = (const float*)d_in[0];
    const float* b = (const float*)d_in[1];
    float* out = (float*)d_out;
    char* ws = (char*)d_ws;

    u8*    aF      = (u8*)ws;                                    // 4 MB
    u8*    bF      = (u8*)(ws + (size_t)4 * 1024 * 1024);        // 4 MB
    float* sumsq_a = (float*)(ws + (size_t)8 * 1024 * 1024);     // 64 KB
    float* sumsq_b = sumsq_a + HW;
    u64*   packed  = (u64*)(sumsq_b + HW);                       // 128 KB

    hipMemsetAsync(out, 0, sizeof(float), stream);
    hipMemsetAsync(packed, 0, (size_t)HW * sizeof(u64), stream);

    prep_kernel<<<dim3(HW / 32), 256, 0, stream>>>(a, b, sumsq_a, sumsq_b, aF, bF);
    gemm_argmax<<<dim3((HW / BM) * (HW / NG)), 256, 0, stream>>>(aF, bF, packed);
    loss_kernel<<<dim3(HW / 256), 256, 0, stream>>>(packed, sumsq_a, sumsq_b, out);
}